// Round 12
// baseline (531.523 us; speedup 1.0000x reference)
//
#include <hip/hip_runtime.h>

typedef _Float16 f16;
typedef _Float16 f16x8 __attribute__((ext_vector_type(8)));
typedef float f32x4 __attribute__((ext_vector_type(4)));

#define SEQ   196
#define EMB   768
#define NHEAD 12
#define HD    64
#define BATCH 256
#define TOK   (BATCH*SEQ)      /* 50176 */
#define QKVN  (3*EMB)          /* 2304  */
#define CLSK  (SEQ*EMB)        /* 150528 */

#define GLD16(gp, lp) __builtin_amdgcn_global_load_lds( \
    (const __attribute__((address_space(1))) void*)(gp), \
    (__attribute__((address_space(3))) void*)(lp), 16, 0, 0)

// ---------------- f32 -> f16 convert, 8 elems/thread ----------------
__global__ __launch_bounds__(256) void k_cvt8(const float* __restrict__ in,
                                              f16* __restrict__ out, int n8) {
  int i = blockIdx.x * 256 + threadIdx.x;
  if (i >= n8) return;
  const float4* p = (const float4*)in + (size_t)i * 2;
  float4 a = p[0], b = p[1];
  f16x8 o;
  o[0]=(f16)a.x; o[1]=(f16)a.y; o[2]=(f16)a.z; o[3]=(f16)a.w;
  o[4]=(f16)b.x; o[5]=(f16)b.y; o[6]=(f16)b.z; o[7]=(f16)b.w;
  *((f16x8*)out + i) = o;
}

// ------------- W[K][N] f32 -> WT[N][K] f16 (tiled transpose) -------------
__global__ __launch_bounds__(256) void k_transpose_cvt(const float* __restrict__ W,
                                                       f16* __restrict__ WT,
                                                       int K, int N) {
  __shared__ float tile[32][33];
  int n0 = blockIdx.x * 32, k0 = blockIdx.y * 32;
  int t = threadIdx.x, tx = t & 31, ty = t >> 5;
  #pragma unroll
  for (int i = 0; i < 4; ++i) {
    int r = ty + i * 8;
    tile[r][tx] = W[(size_t)(k0 + r) * N + n0 + tx];
  }
  __syncthreads();
  #pragma unroll
  for (int i = 0; i < 4; ++i) {
    int r = ty + i * 8;
    WT[(size_t)(n0 + r) * K + k0 + tx] = (f16)tile[tx][r];
  }
}

// ------------- de-interleave cls_w [S*E,3] -> cls16[c*196+s][e] f16 -------
__global__ __launch_bounds__(256) void k_extract_cls(const float* __restrict__ cls_w,
                                                     f16* __restrict__ cls16,
                                                     float* __restrict__ zbias) {
  int idx = blockIdx.x * 256 + threadIdx.x;       // < 588*768 exactly
  int r = idx / EMB, e = idx - r * EMB;
  int c = r / SEQ, s = r - c * SEQ;
  cls16[(size_t)r * EMB + e] = (f16)cls_w[((size_t)s * EMB + e) * 3 + c];
  if (blockIdx.x == 0)
    for (int i = threadIdx.x; i < EMB; i += 256) zbias[i] = 0.f;
}

// ------- const3[c] = cls_b[c] + sum_{s,e} out_b[e]*cls_w[s,e,c] -----------
// 3 blocks (one per class), deterministic tree reduction.
__global__ __launch_bounds__(256) void k_const3(const float* __restrict__ out_b,
                                                const float* __restrict__ cls_w,
                                                const float* __restrict__ cls_b,
                                                float* __restrict__ const3) {
  int c = blockIdx.x, t = threadIdx.x;
  float s = 0.f;
  for (int i = t; i < CLSK; i += 256) s += out_b[i % EMB] * cls_w[(size_t)i * 3 + c];
  __shared__ float red[256];
  red[t] = s;
  __syncthreads();
  for (int off = 128; off > 0; off >>= 1) {
    if (t < off) red[t] += red[t + off];
    __syncthreads();
  }
  if (t == 0) const3[c] = red[0] + cls_b[c];
}

// ------- W2c[(c*196+s)][e] f16 -> W2p[(s*768+e)*4+c] f32 (c=3 pad unused) --
__global__ __launch_bounds__(256) void k_make_w2p(const f16* __restrict__ W2c,
                                                  float* __restrict__ W2p) {
  int idx = blockIdx.x * 256 + threadIdx.x;       // < 588*768 exactly
  int r = idx / EMB, e = idx - r * EMB;
  int c = r / SEQ, s = r - c * SEQ;
  W2p[((size_t)s * EMB + e) * 4 + c] = (float)W2c[idx];
}

// ---------------- f16 GEMM: C[M][N] = A[M][K]*B^T[N][K] + bias -----------
// r2 128x128/BK=64 structure (measured ceiling for this shape: ~222us,
// MfmaUtil 38% -- m97-structure limit) + bijective XCD-chunk swizzle
// (1D grid, bn fastest within bm). Both operands via global_load_lds with
// the both-sides 16B-chunk XOR swizzle -> conflict-free ds_read_b128.
__global__ __launch_bounds__(256) void k_gemm_bias(
    const f16* __restrict__ A, const f16* __restrict__ Bm,
    const float* __restrict__ bias, f16* __restrict__ C,
    int M, int N, int K) {
  __shared__ f16 As[128 * 64];
  __shared__ f16 Bs[128 * 64];
  const int t = threadIdx.x;
  const int l = t & 63;
  const int w = t >> 6;
  const int wr = w >> 1, wc = w & 1;

  const int nwg = gridDim.x;
  const int orig = blockIdx.x;
  const int q = nwg >> 3, r8 = nwg & 7;
  const int xcd = orig & 7, seq = orig >> 3;
  const int base = xcd < r8 ? xcd * (q + 1) : r8 * (q + 1) + (xcd - r8) * q;
  const int wg = base + seq;
  const int NB = N >> 7;
  const int bm = wg / NB, bn = wg - bm * NB;

  const size_t rowA0 = (size_t)bm * 128, rowB0 = (size_t)bn * 128;
  f32x4 acc[4][4] = {};

  for (int k0 = 0; k0 < K; k0 += 64) {
    if (k0) __syncthreads();
    #pragma unroll
    for (int i = 0; i < 4; ++i) {
      int qq = i * 256 + t;
      int rr = qq >> 3, c = qq & 7;
      int cs = c ^ (rr & 7);                     // pre-swizzled source chunk
      const f16* ga = A  + (rowA0 + rr) * K + k0 + cs * 8;
      const f16* gb = Bm + (rowB0 + rr) * K + k0 + cs * 8;
      f16* la = As + (size_t)(i * 256 + w * 64) * 8;  // wave-uniform base
      f16* lb = Bs + (size_t)(i * 256 + w * 64) * 8;
      GLD16(ga, la);
      GLD16(gb, lb);
    }
    __syncthreads();
    #pragma unroll
    for (int ks = 0; ks < 2; ++ks) {
      f16x8 av[4], bv[4];
      const int k8 = ks * 4 + (l >> 4);
      #pragma unroll
      for (int m = 0; m < 4; ++m) {
        int rr = wr * 64 + m * 16 + (l & 15);
        av[m] = *(const f16x8*)((const char*)As + rr * 128 + ((k8 ^ (rr & 7)) << 4));
      }
      #pragma unroll
      for (int n = 0; n < 4; ++n) {
        int rr = wc * 64 + n * 16 + (l & 15);
        bv[n] = *(const f16x8*)((const char*)Bs + rr * 128 + ((k8 ^ (rr & 7)) << 4));
      }
      #pragma unroll
      for (int m = 0; m < 4; ++m)
        #pragma unroll
        for (int n = 0; n < 4; ++n)
          acc[m][n] = __builtin_amdgcn_mfma_f32_16x16x32_f16(av[m], bv[n], acc[m][n], 0, 0, 0);
    }
  }
  // epilogue: C/D layout col = l&15, row = (l>>4)*4 + j  (guide m89/m91)
  #pragma unroll
  for (int n = 0; n < 4; ++n) {
    int gcol = bn * 128 + wc * 64 + n * 16 + (l & 15);
    float bs = bias[gcol];
    #pragma unroll
    for (int m = 0; m < 4; ++m) {
      int grow0 = bm * 128 + wr * 64 + m * 16 + (l >> 4) * 4;
      #pragma unroll
      for (int j = 0; j < 4; ++j)
        C[(size_t)(grow0 + j) * N + gcol] = (f16)(acc[m][n][j] + bs);
    }
  }
}

// ------- fused per-token attention + folded-classifier partial dot --------
// grid (SEQ, BATCH), 64 threads. Computes attn out o[i] in registers and
// immediately dots with W2p row s (L2-resident 12KB): part4[tok] = (s0,s1,s2).
// Staging via uint4 (16B/lane): 288 x 16B = 4608B row.
__global__ __launch_bounds__(64) void k_attn_cls(const f16* __restrict__ qkv,
                                                 const float* __restrict__ W2p,
                                                 float* __restrict__ part4) {
  const int s = blockIdx.x, b = blockIdx.y;
  const int tok = b * SEQ + s;
  const int l = threadIdx.x;
  __shared__ __align__(16) f16 row[QKVN];
  __shared__ float sc[144];
  __shared__ float aw[144];
  const uint4* src4 = (const uint4*)(qkv + (size_t)tok * QKVN);
  uint4* dst4 = (uint4*)row;
  #pragma unroll
  for (int i = 0; i < 4; ++i) dst4[l + i * 64] = src4[l + i * 64];
  if (l < 32) dst4[256 + l] = src4[256 + l];
  __syncthreads();
  for (int p = l; p < 144; p += 64) {
    int i = p / 12, j = p - i * 12;
    const f16x8* q8 = (const f16x8*)(row + i * 192);
    const f16x8* k8 = (const f16x8*)(row + j * 192 + 64);
    float sv = 0.f;
    #pragma unroll
    for (int d8 = 0; d8 < 8; ++d8) {
      f16x8 a = q8[d8], bb = k8[d8];
      #pragma unroll
      for (int e = 0; e < 8; ++e) sv += (float)a[e] * (float)bb[e];
    }
    sc[p] = sv * 0.125f;
  }
  __syncthreads();
  if (l < 12) {
    float m = -1e30f;
    #pragma unroll
    for (int j = 0; j < 12; ++j) m = fmaxf(m, sc[l * 12 + j]);
    float e[12], sum = 0.f;
    #pragma unroll
    for (int j = 0; j < 12; ++j) { e[j] = __expf(sc[l * 12 + j] - m); sum += e[j]; }
    float inv = 1.f / sum;
    #pragma unroll
    for (int j = 0; j < 12; ++j) aw[l * 12 + j] = e[j] * inv;
  }
  __syncthreads();
  float vv[12];
  #pragma unroll
  for (int j = 0; j < 12; ++j) vv[j] = (float)row[j * 192 + 128 + l];
  const float4* wrow = (const float4*)W2p + (size_t)s * EMB;
  float s0 = 0.f, s1 = 0.f, s2 = 0.f;
  #pragma unroll
  for (int i = 0; i < 12; ++i) {
    float o = 0.f;
    #pragma unroll
    for (int j = 0; j < 12; ++j) o += aw[i * 12 + j] * vv[j];
    float4 wv = wrow[i * 64 + l];
    s0 += o * wv.x; s1 += o * wv.y; s2 += o * wv.z;
  }
  #pragma unroll
  for (int off = 32; off > 0; off >>= 1) {
    s0 += __shfl_down(s0, off, 64);
    s1 += __shfl_down(s1, off, 64);
    s2 += __shfl_down(s2, off, 64);
  }
  if (l == 0) *(float4*)(part4 + (size_t)tok * 4) = make_float4(s0, s1, s2, 0.f);
}

// ------- final: logits[b,c] = sum_s part4[b,s,c] + const3[c] --------------
__global__ __launch_bounds__(64) void k_cls_final(const float* __restrict__ part4,
                                                  const float* __restrict__ const3,
                                                  float* __restrict__ logits) {
  const int b = blockIdx.x, l = threadIdx.x;
  float s0 = 0.f, s1 = 0.f, s2 = 0.f;
  for (int j = l; j < SEQ; j += 64) {
    float4 p = *(const float4*)(part4 + ((size_t)b * SEQ + j) * 4);
    s0 += p.x; s1 += p.y; s2 += p.z;
  }
  #pragma unroll
  for (int off = 32; off > 0; off >>= 1) {
    s0 += __shfl_down(s0, off, 64);
    s1 += __shfl_down(s1, off, 64);
    s2 += __shfl_down(s2, off, 64);
  }
  if (l == 0) {
    logits[b * 3 + 0] = s0 + const3[0];
    logits[b * 3 + 1] = s1 + const3[1];
    logits[b * 3 + 2] = s2 + const3[2];
  }
}

extern "C" void kernel_launch(void* const* d_in, const int* in_sizes, int n_in,
                              void* d_out, int out_size, void* d_ws, size_t ws_size,
                              hipStream_t stream) {
  (void)in_sizes; (void)n_in; (void)out_size;
  const float* x      = (const float*)d_in[0];
  const float* qkv_w  = (const float*)d_in[1];
  const float* qkv_b  = (const float*)d_in[2];
  const float* out_w  = (const float*)d_in[3];
  const float* out_b  = (const float*)d_in[4];
  const float* cls_w  = (const float*)d_in[5];
  const float* cls_b  = (const float*)d_in[6];
  float* logits = (float*)d_out;

  // ws layout:
  //  region0 [0, 77MB): x16 during GEMM1; after GEMM1 (x16 dead, prep runs
  //  AFTER G1 in stream order) overlaid by prep + fused-cls buffers:
  //    W2p @0 (2.4MB), outw16 @4MB, cls16 @8MB, W2c @12MB,
  //    part4 @20MB, zbias @24MB, const3 @25MB
  //  qkvb @ SZ_X16 (231MB, live until attn_cls), qkvT @ base2 (3.5MB)
  const size_t SZ_X16 = (size_t)TOK * EMB * 2;      // 77,070,336
  const size_t SZ_QKV = (size_t)TOK * QKVN * 2;     // 231,211,008
  const size_t SZ_QT  = (size_t)QKVN * EMB * 2;     // 3,538,944
  const size_t SZ_OT  = (size_t)EMB * EMB * 2;      // 1,179,648
  if (ws_size < SZ_X16 + SZ_QKV + SZ_QT + SZ_OT) return;

  char* ws = (char*)d_ws;
  const size_t base2 = SZ_X16 + SZ_QKV;
  f16*   x16     = (f16*)ws;
  float* W2p     = (float*)(ws);                        // overlays x16 (post-G1)
  f16*   outw16  = (f16*)(ws + (4u << 20));
  f16*   cls16   = (f16*)(ws + (8u << 20));
  f16*   W2c     = (f16*)(ws + (12u << 20));
  float* part4   = (float*)(ws + (20u << 20));
  float* zbias   = (float*)(ws + (24u << 20));
  float* const3  = (float*)(ws + (25u << 20));
  f16*   qkvb    = (f16*)(ws + SZ_X16);
  f16*   qkvT    = (f16*)(ws + base2);

  // ---- GEMM1 path (proven r6/r8/r10 kernels) ----
  k_cvt8<<<dim3(TOK * EMB / 8 / 256), dim3(256), 0, stream>>>(x, x16, TOK * EMB / 8);
  k_transpose_cvt<<<dim3(QKVN / 32, EMB / 32), dim3(256), 0, stream>>>(qkv_w, qkvT, EMB, QKVN);
  k_gemm_bias<<<dim3((TOK / 128) * (QKVN / 128)), dim3(256), 0, stream>>>(x16, qkvT, qkv_b, qkvb, TOK, QKVN, EMB);
  // ---- folded-classifier prep (x16/qkvT dead; region0 reused) ----
  k_cvt8<<<dim3(EMB * EMB / 8 / 256), dim3(256), 0, stream>>>(out_w, outw16, EMB * EMB / 8);
  k_extract_cls<<<dim3(588 * EMB / 256), dim3(256), 0, stream>>>(cls_w, cls16, zbias);
  k_const3<<<dim3(3), dim3(256), 0, stream>>>(out_b, cls_w, cls_b, const3);
  k_gemm_bias<<<dim3((640 / 128) * (EMB / 128)), dim3(256), 0, stream>>>(cls16, outw16, zbias, W2c, 640, EMB, EMB);
  k_make_w2p<<<dim3(588 * EMB / 256), dim3(256), 0, stream>>>(W2c, W2p);
  // ---- fused attention + classifier ----
  k_attn_cls<<<dim3(SEQ, BATCH), dim3(64), 0, stream>>>(qkvb, W2p, part4);
  k_cls_final<<<dim3(BATCH), dim3(64), 0, stream>>>(part4, const3, logits);
}

// Round 15
// 373.441 us; speedup vs baseline: 1.4233x; 1.4233x over previous
//
#include <hip/hip_runtime.h>

typedef _Float16 f16;
typedef _Float16 f16x8 __attribute__((ext_vector_type(8)));
typedef float f32x4 __attribute__((ext_vector_type(4)));

#define SEQ   196
#define EMB   768
#define NHEAD 12
#define HD    64
#define BATCH 256
#define TOK   (BATCH*SEQ)      /* 50176 */
#define QKVN  (3*EMB)          /* 2304  */
#define CLSK  (SEQ*EMB)        /* 150528 */

#define GLD16(gp, lp) __builtin_amdgcn_global_load_lds( \
    (const __attribute__((address_space(1))) void*)(gp), \
    (__attribute__((address_space(3))) void*)(lp), 16, 0, 0)

// ---------------- f32 -> f16 convert, 8 elems/thread ----------------
__global__ __launch_bounds__(256) void k_cvt8(const float* __restrict__ in,
                                              f16* __restrict__ out, int n8) {
  int i = blockIdx.x * 256 + threadIdx.x;
  if (i >= n8) return;
  const float4* p = (const float4*)in + (size_t)i * 2;
  float4 a = p[0], b = p[1];
  f16x8 o;
  o[0]=(f16)a.x; o[1]=(f16)a.y; o[2]=(f16)a.z; o[3]=(f16)a.w;
  o[4]=(f16)b.x; o[5]=(f16)b.y; o[6]=(f16)b.z; o[7]=(f16)b.w;
  *((f16x8*)out + i) = o;
}

// ------------- W[K][N] f32 -> WT[N][K] f16 (tiled transpose) -------------
__global__ __launch_bounds__(256) void k_transpose_cvt(const float* __restrict__ W,
                                                       f16* __restrict__ WT,
                                                       int K, int N) {
  __shared__ float tile[32][33];
  int n0 = blockIdx.x * 32, k0 = blockIdx.y * 32;
  int t = threadIdx.x, tx = t & 31, ty = t >> 5;
  #pragma unroll
  for (int i = 0; i < 4; ++i) {
    int r = ty + i * 8;
    tile[r][tx] = W[(size_t)(k0 + r) * N + n0 + tx];
  }
  __syncthreads();
  #pragma unroll
  for (int i = 0; i < 4; ++i) {
    int r = ty + i * 8;
    WT[(size_t)(n0 + r) * K + k0 + tx] = (f16)tile[tx][r];
  }
}

// ------------- de-interleave cls_w [S*E,3] -> cls16[c*196+s][e] f16 -------
__global__ __launch_bounds__(256) void k_extract_cls(const float* __restrict__ cls_w,
                                                     f16* __restrict__ cls16,
                                                     float* __restrict__ zbias) {
  int idx = blockIdx.x * 256 + threadIdx.x;       // < 588*768 exactly
  int r = idx / EMB, e = idx - r * EMB;
  int c = r / SEQ, s = r - c * SEQ;
  cls16[(size_t)r * EMB + e] = (f16)cls_w[((size_t)s * EMB + e) * 3 + c];
  if (blockIdx.x == 0)
    for (int i = threadIdx.x; i < EMB; i += 256) zbias[i] = 0.f;
}

// ------- const3 stage 1: partial[s][c] = sum_e out_b[e]*cls_w[s,e,c] -------
// 196 blocks (NOT 3 -- the merged 3-block variant was the r7/r12 ~150us
// gremlin: 3 CUs, stride-12 reads, latency-bound).
__global__ __launch_bounds__(256) void k_const3a(const float* __restrict__ out_b,
                                                 const float* __restrict__ cls_w,
                                                 float* __restrict__ partial) {
  int s = blockIdx.x, t = threadIdx.x;
  float a0 = 0.f, a1 = 0.f, a2 = 0.f;
  for (int e = t; e < EMB; e += 256) {
    float ob = out_b[e];
    const float* p = cls_w + ((size_t)s * EMB + e) * 3;
    a0 += ob * p[0]; a1 += ob * p[1]; a2 += ob * p[2];
  }
  __shared__ float r0[256], r1[256], r2[256];
  r0[t] = a0; r1[t] = a1; r2[t] = a2;
  __syncthreads();
  for (int off = 128; off > 0; off >>= 1) {
    if (t < off) { r0[t] += r0[t + off]; r1[t] += r1[t + off]; r2[t] += r2[t + off]; }
    __syncthreads();
  }
  if (t == 0) { partial[s * 3 + 0] = r0[0]; partial[s * 3 + 1] = r1[0]; partial[s * 3 + 2] = r2[0]; }
}

// ------- const3 stage 2: const3[c] = cls_b[c] + sum_s partial[s][c] --------
__global__ __launch_bounds__(64) void k_const3b(const float* __restrict__ partial,
                                                const float* __restrict__ cls_b,
                                                float* __restrict__ const3) {
  int t = threadIdx.x;
  #pragma unroll
  for (int c = 0; c < 3; ++c) {
    float s = 0.f;
    for (int j = t; j < SEQ; j += 64) s += partial[j * 3 + c];
    #pragma unroll
    for (int off = 32; off > 0; off >>= 1) s += __shfl_down(s, off, 64);
    if (t == 0) const3[c] = s + cls_b[c];
  }
}

// ------- W2c[(c*196+s)][e] f16 -> W2p[(s*768+e)*4+c] f32 (c=3 pad unused) --
__global__ __launch_bounds__(256) void k_make_w2p(const f16* __restrict__ W2c,
                                                  float* __restrict__ W2p) {
  int idx = blockIdx.x * 256 + threadIdx.x;       // < 588*768 exactly
  int r = idx / EMB, e = idx - r * EMB;
  int c = r / SEQ, s = r - c * SEQ;
  W2p[((size_t)s * EMB + e) * 4 + c] = (float)W2c[idx];
}

// ---------------- f16 GEMM: C[M][N] = A[M][K]*B^T[N][K] + bias -----------
// r2 128x128/BK=64 structure (measured ceiling for this shape: ~222us,
// MfmaUtil 38% -- m97-structure limit) + bijective XCD-chunk swizzle
// (1D grid, bn fastest within bm). Both operands via global_load_lds with
// the both-sides 16B-chunk XOR swizzle -> conflict-free ds_read_b128.
__global__ __launch_bounds__(256) void k_gemm_bias(
    const f16* __restrict__ A, const f16* __restrict__ Bm,
    const float* __restrict__ bias, f16* __restrict__ C,
    int M, int N, int K) {
  __shared__ f16 As[128 * 64];
  __shared__ f16 Bs[128 * 64];
  const int t = threadIdx.x;
  const int l = t & 63;
  const int w = t >> 6;
  const int wr = w >> 1, wc = w & 1;

  const int nwg = gridDim.x;
  const int orig = blockIdx.x;
  const int q = nwg >> 3, r8 = nwg & 7;
  const int xcd = orig & 7, seq = orig >> 3;
  const int base = xcd < r8 ? xcd * (q + 1) : r8 * (q + 1) + (xcd - r8) * q;
  const int wg = base + seq;
  const int NB = N >> 7;
  const int bm = wg / NB, bn = wg - bm * NB;

  const size_t rowA0 = (size_t)bm * 128, rowB0 = (size_t)bn * 128;
  f32x4 acc[4][4] = {};

  for (int k0 = 0; k0 < K; k0 += 64) {
    if (k0) __syncthreads();
    #pragma unroll
    for (int i = 0; i < 4; ++i) {
      int qq = i * 256 + t;
      int rr = qq >> 3, c = qq & 7;
      int cs = c ^ (rr & 7);                     // pre-swizzled source chunk
      const f16* ga = A  + (rowA0 + rr) * K + k0 + cs * 8;
      const f16* gb = Bm + (rowB0 + rr) * K + k0 + cs * 8;
      f16* la = As + (size_t)(i * 256 + w * 64) * 8;  // wave-uniform base
      f16* lb = Bs + (size_t)(i * 256 + w * 64) * 8;
      GLD16(ga, la);
      GLD16(gb, lb);
    }
    __syncthreads();
    #pragma unroll
    for (int ks = 0; ks < 2; ++ks) {
      f16x8 av[4], bv[4];
      const int k8 = ks * 4 + (l >> 4);
      #pragma unroll
      for (int m = 0; m < 4; ++m) {
        int rr = wr * 64 + m * 16 + (l & 15);
        av[m] = *(const f16x8*)((const char*)As + rr * 128 + ((k8 ^ (rr & 7)) << 4));
      }
      #pragma unroll
      for (int n = 0; n < 4; ++n) {
        int rr = wc * 64 + n * 16 + (l & 15);
        bv[n] = *(const f16x8*)((const char*)Bs + rr * 128 + ((k8 ^ (rr & 7)) << 4));
      }
      #pragma unroll
      for (int m = 0; m < 4; ++m)
        #pragma unroll
        for (int n = 0; n < 4; ++n)
          acc[m][n] = __builtin_amdgcn_mfma_f32_16x16x32_f16(av[m], bv[n], acc[m][n], 0, 0, 0);
    }
  }
  // epilogue: C/D layout col = l&15, row = (l>>4)*4 + j  (guide m89/m91)
  #pragma unroll
  for (int n = 0; n < 4; ++n) {
    int gcol = bn * 128 + wc * 64 + n * 16 + (l & 15);
    float bs = bias[gcol];
    #pragma unroll
    for (int m = 0; m < 4; ++m) {
      int grow0 = bm * 128 + wr * 64 + m * 16 + (l >> 4) * 4;
      #pragma unroll
      for (int j = 0; j < 4; ++j)
        C[(size_t)(grow0 + j) * N + gcol] = (f16)(acc[m][n][j] + bs);
    }
  }
}

// ------- fused per-token attention + folded-classifier partial dot --------
// grid (SEQ, BATCH), 64 threads. Staging via uint4 (16B/lane).
__global__ __launch_bounds__(64) void k_attn_cls(const f16* __restrict__ qkv,
                                                 const float* __restrict__ W2p,
                                                 float* __restrict__ part4) {
  const int s = blockIdx.x, b = blockIdx.y;
  const int tok = b * SEQ + s;
  const int l = threadIdx.x;
  __shared__ __align__(16) f16 row[QKVN];
  __shared__ float sc[144];
  __shared__ float aw[144];
  const uint4* src4 = (const uint4*)(qkv + (size_t)tok * QKVN);
  uint4* dst4 = (uint4*)row;
  #pragma unroll
  for (int i = 0; i < 4; ++i) dst4[l + i * 64] = src4[l + i * 64];
  if (l < 32) dst4[256 + l] = src4[256 + l];
  __syncthreads();
  for (int p = l; p < 144; p += 64) {
    int i = p / 12, j = p - i * 12;
    const f16x8* q8 = (const f16x8*)(row + i * 192);
    const f16x8* k8 = (const f16x8*)(row + j * 192 + 64);
    float sv = 0.f;
    #pragma unroll
    for (int d8 = 0; d8 < 8; ++d8) {
      f16x8 a = q8[d8], bb = k8[d8];
      #pragma unroll
      for (int e = 0; e < 8; ++e) sv += (float)a[e] * (float)bb[e];
    }
    sc[p] = sv * 0.125f;
  }
  __syncthreads();
  if (l < 12) {
    float m = -1e30f;
    #pragma unroll
    for (int j = 0; j < 12; ++j) m = fmaxf(m, sc[l * 12 + j]);
    float e[12], sum = 0.f;
    #pragma unroll
    for (int j = 0; j < 12; ++j) { e[j] = __expf(sc[l * 12 + j] - m); sum += e[j]; }
    float inv = 1.f / sum;
    #pragma unroll
    for (int j = 0; j < 12; ++j) aw[l * 12 + j] = e[j] * inv;
  }
  __syncthreads();
  float vv[12];
  #pragma unroll
  for (int j = 0; j < 12; ++j) vv[j] = (float)row[j * 192 + 128 + l];
  const float4* wrow = (const float4*)W2p + (size_t)s * EMB;
  float s0 = 0.f, s1 = 0.f, s2 = 0.f;
  #pragma unroll
  for (int i = 0; i < 12; ++i) {
    float o = 0.f;
    #pragma unroll
    for (int j = 0; j < 12; ++j) o += aw[i * 12 + j] * vv[j];
    float4 wv = wrow[i * 64 + l];
    s0 += o * wv.x; s1 += o * wv.y; s2 += o * wv.z;
  }
  #pragma unroll
  for (int off = 32; off > 0; off >>= 1) {
    s0 += __shfl_down(s0, off, 64);
    s1 += __shfl_down(s1, off, 64);
    s2 += __shfl_down(s2, off, 64);
  }
  if (l == 0) *(float4*)(part4 + (size_t)tok * 4) = make_float4(s0, s1, s2, 0.f);
}

// ------- final: logits[b,c] = sum_s part4[b,s,c] + const3[c] --------------
__global__ __launch_bounds__(64) void k_cls_final(const float* __restrict__ part4,
                                                  const float* __restrict__ const3,
                                                  float* __restrict__ logits) {
  const int b = blockIdx.x, l = threadIdx.x;
  float s0 = 0.f, s1 = 0.f, s2 = 0.f;
  for (int j = l; j < SEQ; j += 64) {
    float4 p = *(const float4*)(part4 + ((size_t)b * SEQ + j) * 4);
    s0 += p.x; s1 += p.y; s2 += p.z;
  }
  #pragma unroll
  for (int off = 32; off > 0; off >>= 1) {
    s0 += __shfl_down(s0, off, 64);
    s1 += __shfl_down(s1, off, 64);
    s2 += __shfl_down(s2, off, 64);
  }
  if (l == 0) {
    logits[b * 3 + 0] = s0 + const3[0];
    logits[b * 3 + 1] = s1 + const3[1];
    logits[b * 3 + 2] = s2 + const3[2];
  }
}

extern "C" void kernel_launch(void* const* d_in, const int* in_sizes, int n_in,
                              void* d_out, int out_size, void* d_ws, size_t ws_size,
                              hipStream_t stream) {
  (void)in_sizes; (void)n_in; (void)out_size;
  const float* x      = (const float*)d_in[0];
  const float* qkv_w  = (const float*)d_in[1];
  const float* qkv_b  = (const float*)d_in[2];
  const float* out_w  = (const float*)d_in[3];
  const float* out_b  = (const float*)d_in[4];
  const float* cls_w  = (const float*)d_in[5];
  const float* cls_b  = (const float*)d_in[6];
  float* logits = (float*)d_out;

  // ws layout:
  //  region0 [0, 77MB): x16 during GEMM1; after GEMM1 (x16 dead, prep runs
  //  AFTER G1 in stream order) overlaid by prep + fused-cls buffers:
  //    W2p @0 (2.4MB), outw16 @4MB, cls16 @8MB, W2c @12MB, partial @16MB,
  //    part4 @20MB, zbias @24MB, const3 @25MB
  //  qkvb @ SZ_X16 (231MB, live until attn_cls), qkvT @ base2 (3.5MB)
  const size_t SZ_X16 = (size_t)TOK * EMB * 2;      // 77,070,336
  const size_t SZ_QKV = (size_t)TOK * QKVN * 2;     // 231,211,008
  const size_t SZ_QT  = (size_t)QKVN * EMB * 2;     // 3,538,944
  const size_t SZ_OT  = (size_t)EMB * EMB * 2;      // 1,179,648
  if (ws_size < SZ_X16 + SZ_QKV + SZ_QT + SZ_OT) return;

  char* ws = (char*)d_ws;
  const size_t base2 = SZ_X16 + SZ_QKV;
  f16*   x16     = (f16*)ws;
  float* W2p     = (float*)(ws);                        // overlays x16 (post-G1)
  f16*   outw16  = (f16*)(ws + (4u << 20));
  f16*   cls16   = (f16*)(ws + (8u << 20));
  f16*   W2c     = (f16*)(ws + (12u << 20));
  float* partial = (float*)(ws + (16u << 20));
  float* part4   = (float*)(ws + (20u << 20));
  float* zbias   = (float*)(ws + (24u << 20));
  float* const3  = (float*)(ws + (25u << 20));
  f16*   qkvb    = (f16*)(ws + SZ_X16);
  f16*   qkvT    = (f16*)(ws + base2);

  // ---- GEMM1 path (proven r6/r8/r10 kernels) ----
  k_cvt8<<<dim3(TOK * EMB / 8 / 256), dim3(256), 0, stream>>>(x, x16, TOK * EMB / 8);
  k_transpose_cvt<<<dim3(QKVN / 32, EMB / 32), dim3(256), 0, stream>>>(qkv_w, qkvT, EMB, QKVN);
  k_gemm_bias<<<dim3((TOK / 128) * (QKVN / 128)), dim3(256), 0, stream>>>(x16, qkvT, qkv_b, qkvb, TOK, QKVN, EMB);
  // ---- folded-classifier prep (x16/qkvT dead; region0 reused) ----
  k_cvt8<<<dim3(EMB * EMB / 8 / 256), dim3(256), 0, stream>>>(out_w, outw16, EMB * EMB / 8);
  k_extract_cls<<<dim3(588 * EMB / 256), dim3(256), 0, stream>>>(cls_w, cls16, zbias);
  k_const3a<<<dim3(SEQ), dim3(256), 0, stream>>>(out_b, cls_w, partial);
  k_const3b<<<dim3(1), dim3(64), 0, stream>>>(partial, cls_b, const3);
  k_gemm_bias<<<dim3((640 / 128) * (EMB / 128)), dim3(256), 0, stream>>>(cls16, outw16, zbias, W2c, 640, EMB, EMB);
  k_make_w2p<<<dim3(588 * EMB / 256), dim3(256), 0, stream>>>(W2c, W2p);
  // ---- fused attention + classifier ----
  k_attn_cls<<<dim3(SEQ, BATCH), dim3(64), 0, stream>>>(qkvb, W2p, part4);
  k_cls_final<<<dim3(BATCH), dim3(64), 0, stream>>>(part4, const3, logits);
}

// Round 16
// 371.077 us; speedup vs baseline: 1.4324x; 1.0064x over previous
//
#include <hip/hip_runtime.h>

typedef _Float16 f16;
typedef _Float16 f16x8 __attribute__((ext_vector_type(8)));
typedef float f32x4 __attribute__((ext_vector_type(4)));

#define SEQ   196
#define EMB   768
#define NHEAD 12
#define HD    64
#define BATCH 256
#define TOK   (BATCH*SEQ)      /* 50176 */
#define QKVN  (3*EMB)          /* 2304  */
#define CLSK  (SEQ*EMB)        /* 150528 */

#define N_CVT 288              /* EMB*EMB/8/256 */
#define N_EXT 1764             /* 588*EMB/256   */
#define N_C3A SEQ              /* 196           */

#define GLD16(gp, lp) __builtin_amdgcn_global_load_lds( \
    (const __attribute__((address_space(1))) void*)(gp), \
    (__attribute__((address_space(3))) void*)(lp), 16, 0, 0)

// ---------------- f32 -> f16 convert, 8 elems/thread ----------------
__global__ __launch_bounds__(256) void k_cvt8(const float* __restrict__ in,
                                              f16* __restrict__ out, int n8) {
  int i = blockIdx.x * 256 + threadIdx.x;
  if (i >= n8) return;
  const float4* p = (const float4*)in + (size_t)i * 2;
  float4 a = p[0], b = p[1];
  f16x8 o;
  o[0]=(f16)a.x; o[1]=(f16)a.y; o[2]=(f16)a.z; o[3]=(f16)a.w;
  o[4]=(f16)b.x; o[5]=(f16)b.y; o[6]=(f16)b.z; o[7]=(f16)b.w;
  *((f16x8*)out + i) = o;
}

// ------------- W[K][N] f32 -> WT[N][K] f16 (tiled transpose) -------------
__global__ __launch_bounds__(256) void k_transpose_cvt(const float* __restrict__ W,
                                                       f16* __restrict__ WT,
                                                       int K, int N) {
  __shared__ float tile[32][33];
  int n0 = blockIdx.x * 32, k0 = blockIdx.y * 32;
  int t = threadIdx.x, tx = t & 31, ty = t >> 5;
  #pragma unroll
  for (int i = 0; i < 4; ++i) {
    int r = ty + i * 8;
    tile[r][tx] = W[(size_t)(k0 + r) * N + n0 + tx];
  }
  __syncthreads();
  #pragma unroll
  for (int i = 0; i < 4; ++i) {
    int r = ty + i * 8;
    WT[(size_t)(n0 + r) * K + k0 + tx] = (f16)tile[tx][r];
  }
}

// ---- merged prep stage 1: {cvt8(out_w) | extract_cls+zbias | const3a} ----
// Grid-branch merge of three PROVEN bodies (launch-overhead reduction only;
// access patterns byte-identical to the r10/r15 split kernels).
__global__ __launch_bounds__(256) void k_prep1(const float* __restrict__ out_w,
                                               f16* __restrict__ outw16,
                                               const float* __restrict__ cls_w,
                                               f16* __restrict__ cls16,
                                               float* __restrict__ zbias,
                                               const float* __restrict__ out_b,
                                               float* __restrict__ partial) {
  const int b = blockIdx.x, t = threadIdx.x;
  if (b < N_CVT) {
    // ---- cvt8: out_w -> outw16 (73728 vec8s, exact) ----
    int i = b * 256 + t;
    const float4* p = (const float4*)out_w + (size_t)i * 2;
    float4 a = p[0], v = p[1];
    f16x8 o;
    o[0]=(f16)a.x; o[1]=(f16)a.y; o[2]=(f16)a.z; o[3]=(f16)a.w;
    o[4]=(f16)v.x; o[5]=(f16)v.y; o[6]=(f16)v.z; o[7]=(f16)v.w;
    *((f16x8*)outw16 + i) = o;
  } else if (b < N_CVT + N_EXT) {
    // ---- extract_cls: de-interleave cls_w -> cls16[c*196+s][e] ----
    int idx = (b - N_CVT) * 256 + t;
    int r = idx / EMB, e = idx - r * EMB;
    int c = r / SEQ, s = r - c * SEQ;
    cls16[(size_t)r * EMB + e] = (f16)cls_w[((size_t)s * EMB + e) * 3 + c];
    if (b == N_CVT)
      for (int i = t; i < EMB; i += 256) zbias[i] = 0.f;
  } else {
    // ---- const3a: partial[s][c] = sum_e out_b[e]*cls_w[s,e,c] ----
    // (196 wide blocks -- NEVER the 3-block merged form: r7/r12 gremlin)
    int s = b - (N_CVT + N_EXT);
    float a0 = 0.f, a1 = 0.f, a2 = 0.f;
    for (int e = t; e < EMB; e += 256) {
      float ob = out_b[e];
      const float* p = cls_w + ((size_t)s * EMB + e) * 3;
      a0 += ob * p[0]; a1 += ob * p[1]; a2 += ob * p[2];
    }
    __shared__ float r0[256], r1[256], r2[256];
    r0[t] = a0; r1[t] = a1; r2[t] = a2;
    __syncthreads();
    for (int off = 128; off > 0; off >>= 1) {
      if (t < off) { r0[t] += r0[t + off]; r1[t] += r1[t + off]; r2[t] += r2[t + off]; }
      __syncthreads();
    }
    if (t == 0) { partial[s * 3 + 0] = r0[0]; partial[s * 3 + 1] = r1[0]; partial[s * 3 + 2] = r2[0]; }
  }
}

// ---- merged prep stage 2: {make_w2p | const3b} (after W2 gemm) ----
__global__ __launch_bounds__(256) void k_prep2(const f16* __restrict__ W2c,
                                               float* __restrict__ W2p,
                                               const float* __restrict__ partial,
                                               const float* __restrict__ cls_b,
                                               float* __restrict__ const3) {
  const int b = blockIdx.x, t = threadIdx.x;
  if (b < N_EXT) {
    // ---- make_w2p: W2c[(c*196+s)][e] f16 -> W2p[(s*768+e)*4+c] f32 ----
    int idx = b * 256 + t;
    int r = idx / EMB, e = idx - r * EMB;
    int c = r / SEQ, s = r - c * SEQ;
    W2p[((size_t)s * EMB + e) * 4 + c] = (float)W2c[idx];
  } else {
    // ---- const3b: const3[c] = cls_b[c] + sum_s partial[s][c] ----
    // wave 0 does the work (stride 64, t==0 writes); other waves idle-safe.
    #pragma unroll
    for (int c = 0; c < 3; ++c) {
      float s = 0.f;
      for (int j = t; j < SEQ; j += 64) s += partial[j * 3 + c];
      #pragma unroll
      for (int off = 32; off > 0; off >>= 1) s += __shfl_down(s, off, 64);
      if (t == 0) const3[c] = s + cls_b[c];
    }
  }
}

// ---------------- f16 GEMM: C[M][N] = A[M][K]*B^T[N][K] + bias -----------
// r2 128x128/BK=64 structure (measured ceiling for this shape: ~222us,
// MfmaUtil 38% -- m97-structure limit) + bijective XCD-chunk swizzle
// (1D grid, bn fastest within bm). Both operands via global_load_lds with
// the both-sides 16B-chunk XOR swizzle -> conflict-free ds_read_b128.
__global__ __launch_bounds__(256) void k_gemm_bias(
    const f16* __restrict__ A, const f16* __restrict__ Bm,
    const float* __restrict__ bias, f16* __restrict__ C,
    int M, int N, int K) {
  __shared__ f16 As[128 * 64];
  __shared__ f16 Bs[128 * 64];
  const int t = threadIdx.x;
  const int l = t & 63;
  const int w = t >> 6;
  const int wr = w >> 1, wc = w & 1;

  const int nwg = gridDim.x;
  const int orig = blockIdx.x;
  const int q = nwg >> 3, r8 = nwg & 7;
  const int xcd = orig & 7, seq = orig >> 3;
  const int base = xcd < r8 ? xcd * (q + 1) : r8 * (q + 1) + (xcd - r8) * q;
  const int wg = base + seq;
  const int NB = N >> 7;
  const int bm = wg / NB, bn = wg - bm * NB;

  const size_t rowA0 = (size_t)bm * 128, rowB0 = (size_t)bn * 128;
  f32x4 acc[4][4] = {};

  for (int k0 = 0; k0 < K; k0 += 64) {
    if (k0) __syncthreads();
    #pragma unroll
    for (int i = 0; i < 4; ++i) {
      int qq = i * 256 + t;
      int rr = qq >> 3, c = qq & 7;
      int cs = c ^ (rr & 7);                     // pre-swizzled source chunk
      const f16* ga = A  + (rowA0 + rr) * K + k0 + cs * 8;
      const f16* gb = Bm + (rowB0 + rr) * K + k0 + cs * 8;
      f16* la = As + (size_t)(i * 256 + w * 64) * 8;  // wave-uniform base
      f16* lb = Bs + (size_t)(i * 256 + w * 64) * 8;
      GLD16(ga, la);
      GLD16(gb, lb);
    }
    __syncthreads();
    #pragma unroll
    for (int ks = 0; ks < 2; ++ks) {
      f16x8 av[4], bv[4];
      const int k8 = ks * 4 + (l >> 4);
      #pragma unroll
      for (int m = 0; m < 4; ++m) {
        int rr = wr * 64 + m * 16 + (l & 15);
        av[m] = *(const f16x8*)((const char*)As + rr * 128 + ((k8 ^ (rr & 7)) << 4));
      }
      #pragma unroll
      for (int n = 0; n < 4; ++n) {
        int rr = wc * 64 + n * 16 + (l & 15);
        bv[n] = *(const f16x8*)((const char*)Bs + rr * 128 + ((k8 ^ (rr & 7)) << 4));
      }
      #pragma unroll
      for (int m = 0; m < 4; ++m)
        #pragma unroll
        for (int n = 0; n < 4; ++n)
          acc[m][n] = __builtin_amdgcn_mfma_f32_16x16x32_f16(av[m], bv[n], acc[m][n], 0, 0, 0);
    }
  }
  // epilogue: C/D layout col = l&15, row = (l>>4)*4 + j  (guide m89/m91)
  #pragma unroll
  for (int n = 0; n < 4; ++n) {
    int gcol = bn * 128 + wc * 64 + n * 16 + (l & 15);
    float bs = bias[gcol];
    #pragma unroll
    for (int m = 0; m < 4; ++m) {
      int grow0 = bm * 128 + wr * 64 + m * 16 + (l >> 4) * 4;
      #pragma unroll
      for (int j = 0; j < 4; ++j)
        C[(size_t)(grow0 + j) * N + gcol] = (f16)(acc[m][n][j] + bs);
    }
  }
}

// ------- fused per-token attention + folded-classifier partial dot --------
// grid (SEQ, BATCH), 64 threads. Staging via uint4 (16B/lane).
__global__ __launch_bounds__(64) void k_attn_cls(const f16* __restrict__ qkv,
                                                 const float* __restrict__ W2p,
                                                 float* __restrict__ part4) {
  const int s = blockIdx.x, b = blockIdx.y;
  const int tok = b * SEQ + s;
  const int l = threadIdx.x;
  __shared__ __align__(16) f16 row[QKVN];
  __shared__ float sc[144];
  __shared__ float aw[144];
  const uint4* src4 = (const uint4*)(qkv + (size_t)tok * QKVN);
  uint4* dst4 = (uint4*)row;
  #pragma unroll
  for (int i = 0; i < 4; ++i) dst4[l + i * 64] = src4[l + i * 64];
  if (l < 32) dst4[256 + l] = src4[256 + l];
  __syncthreads();
  for (int p = l; p < 144; p += 64) {
    int i = p / 12, j = p - i * 12;
    const f16x8* q8 = (const f16x8*)(row + i * 192);
    const f16x8* k8 = (const f16x8*)(row + j * 192 + 64);
    float sv = 0.f;
    #pragma unroll
    for (int d8 = 0; d8 < 8; ++d8) {
      f16x8 a = q8[d8], bb = k8[d8];
      #pragma unroll
      for (int e = 0; e < 8; ++e) sv += (float)a[e] * (float)bb[e];
    }
    sc[p] = sv * 0.125f;
  }
  __syncthreads();
  if (l < 12) {
    float m = -1e30f;
    #pragma unroll
    for (int j = 0; j < 12; ++j) m = fmaxf(m, sc[l * 12 + j]);
    float e[12], sum = 0.f;
    #pragma unroll
    for (int j = 0; j < 12; ++j) { e[j] = __expf(sc[l * 12 + j] - m); sum += e[j]; }
    float inv = 1.f / sum;
    #pragma unroll
    for (int j = 0; j < 12; ++j) aw[l * 12 + j] = e[j] * inv;
  }
  __syncthreads();
  float vv[12];
  #pragma unroll
  for (int j = 0; j < 12; ++j) vv[j] = (float)row[j * 192 + 128 + l];
  const float4* wrow = (const float4*)W2p + (size_t)s * EMB;
  float s0 = 0.f, s1 = 0.f, s2 = 0.f;
  #pragma unroll
  for (int i = 0; i < 12; ++i) {
    float o = 0.f;
    #pragma unroll
    for (int j = 0; j < 12; ++j) o += aw[i * 12 + j] * vv[j];
    float4 wv = wrow[i * 64 + l];
    s0 += o * wv.x; s1 += o * wv.y; s2 += o * wv.z;
  }
  #pragma unroll
  for (int off = 32; off > 0; off >>= 1) {
    s0 += __shfl_down(s0, off, 64);
    s1 += __shfl_down(s1, off, 64);
    s2 += __shfl_down(s2, off, 64);
  }
  if (l == 0) *(float4*)(part4 + (size_t)tok * 4) = make_float4(s0, s1, s2, 0.f);
}

// ------- final: logits[b,c] = sum_s part4[b,s,c] + const3[c] --------------
__global__ __launch_bounds__(64) void k_cls_final(const float* __restrict__ part4,
                                                  const float* __restrict__ const3,
                                                  float* __restrict__ logits) {
  const int b = blockIdx.x, l = threadIdx.x;
  float s0 = 0.f, s1 = 0.f, s2 = 0.f;
  for (int j = l; j < SEQ; j += 64) {
    float4 p = *(const float4*)(part4 + ((size_t)b * SEQ + j) * 4);
    s0 += p.x; s1 += p.y; s2 += p.z;
  }
  #pragma unroll
  for (int off = 32; off > 0; off >>= 1) {
    s0 += __shfl_down(s0, off, 64);
    s1 += __shfl_down(s1, off, 64);
    s2 += __shfl_down(s2, off, 64);
  }
  if (l == 0) {
    logits[b * 3 + 0] = s0 + const3[0];
    logits[b * 3 + 1] = s1 + const3[1];
    logits[b * 3 + 2] = s2 + const3[2];
  }
}

extern "C" void kernel_launch(void* const* d_in, const int* in_sizes, int n_in,
                              void* d_out, int out_size, void* d_ws, size_t ws_size,
                              hipStream_t stream) {
  (void)in_sizes; (void)n_in; (void)out_size;
  const float* x      = (const float*)d_in[0];
  const float* qkv_w  = (const float*)d_in[1];
  const float* qkv_b  = (const float*)d_in[2];
  const float* out_w  = (const float*)d_in[3];
  const float* out_b  = (const float*)d_in[4];
  const float* cls_w  = (const float*)d_in[5];
  const float* cls_b  = (const float*)d_in[6];
  float* logits = (float*)d_out;

  // ws layout:
  //  region0 [0, 77MB): x16 during GEMM1; after GEMM1 (x16 dead, prep runs
  //  AFTER G1 in stream order) overlaid by prep + fused-cls buffers:
  //    W2p @0 (2.4MB), outw16 @4MB, cls16 @8MB, W2c @12MB, partial @16MB,
  //    part4 @20MB, zbias @24MB, const3 @25MB
  //  qkvb @ SZ_X16 (231MB, live until attn_cls), qkvT @ base2 (3.5MB)
  const size_t SZ_X16 = (size_t)TOK * EMB * 2;      // 77,070,336
  const size_t SZ_QKV = (size_t)TOK * QKVN * 2;     // 231,211,008
  const size_t SZ_QT  = (size_t)QKVN * EMB * 2;     // 3,538,944
  const size_t SZ_OT  = (size_t)EMB * EMB * 2;      // 1,179,648
  if (ws_size < SZ_X16 + SZ_QKV + SZ_QT + SZ_OT) return;

  char* ws = (char*)d_ws;
  const size_t base2 = SZ_X16 + SZ_QKV;
  f16*   x16     = (f16*)ws;
  float* W2p     = (float*)(ws);                        // overlays x16 (post-G1)
  f16*   outw16  = (f16*)(ws + (4u << 20));
  f16*   cls16   = (f16*)(ws + (8u << 20));
  f16*   W2c     = (f16*)(ws + (12u << 20));
  float* partial = (float*)(ws + (16u << 20));
  float* part4   = (float*)(ws + (20u << 20));
  float* zbias   = (float*)(ws + (24u << 20));
  float* const3  = (float*)(ws + (25u << 20));
  f16*   qkvb    = (f16*)(ws + SZ_X16);
  f16*   qkvT    = (f16*)(ws + base2);

  // ---- GEMM1 path (proven r6/r8/r10 kernels) ----
  k_cvt8<<<dim3(TOK * EMB / 8 / 256), dim3(256), 0, stream>>>(x, x16, TOK * EMB / 8);
  k_transpose_cvt<<<dim3(QKVN / 32, EMB / 32), dim3(256), 0, stream>>>(qkv_w, qkvT, EMB, QKVN);
  k_gemm_bias<<<dim3((TOK / 128) * (QKVN / 128)), dim3(256), 0, stream>>>(x16, qkvT, qkv_b, qkvb, TOK, QKVN, EMB);
  // ---- folded-classifier prep, launch-merged (x16/qkvT dead) ----
  k_prep1<<<dim3(N_CVT + N_EXT + N_C3A), dim3(256), 0, stream>>>(out_w, outw16, cls_w, cls16, zbias, out_b, partial);
  k_gemm_bias<<<dim3((640 / 128) * (EMB / 128)), dim3(256), 0, stream>>>(cls16, outw16, zbias, W2c, 640, EMB, EMB);
  k_prep2<<<dim3(N_EXT + 1), dim3(256), 0, stream>>>(W2c, W2p, partial, cls_b, const3);
  // ---- fused attention + classifier ----
  k_attn_cls<<<dim3(SEQ, BATCH), dim3(64), 0, stream>>>(qkvb, W2p, part4);
  k_cls_final<<<dim3(BATCH), dim3(64), 0, stream>>>(part4, const3, logits);
}